// Round 4
// baseline (1882.311 us; speedup 1.0000x reference)
//
#include <hip/hip_runtime.h>

// N=524288 rows, D_IN=248 (padded to 256), H=64, G=32 groups, OUT=3.
// Pipeline (7 dispatches):
//   prep_weights(split W1 -> bf16 hi/lo, transpose W2/W3/W4)
//   -> gemm1_mfma (split-bf16 3-MFMA fp32-accurate GEMM via inline asm,
//                  fused leaky+stats+count)
//   -> finalize1 -> gemm_h_fused(W2,+stats2) -> finalize2
//   -> gemm_h_fused(W3,+stats3) -> finalize3 -> gemm4.
// MFMA layout assumptions (m89/m92-lineage, documented for debugging):
//   D/C: col = lane&15, row = (lane>>4)*4 + reg     [m89-verified]
//   A  : row = lane&15, k = (lane>>4)*8 + j (j=0..7 contiguous)
//   B  : col = lane&15, k = (lane>>4)*8 + j
// MFMA emitted as inline asm (not the builtin) to be robust against
// builtin operand-type signature drift (short8 vs bf16x8) on ROCm 7.

#define GRP_N 32
#define EPSV 1e-8f
constexpr int DIN = 248;
constexpr int KP  = 256;   // padded K for layer 1
constexpr int H   = 64;
constexpr int ASTR = 40;   // LDS bf16 row stride: 80 B rows -> 16B-aligned b128 frags, ~2-way banks

typedef __attribute__((ext_vector_type(8))) short short8;   // 8 bf16 raw bits = 4 VGPRs
typedef __attribute__((ext_vector_type(4))) float f32x4;

__device__ __forceinline__ void mfma_bf16(f32x4& d, short8 a, short8 b) {
    // d = a(16x32 bf16) * b(32x16 bf16) + d   (C tied to D)
    asm volatile("v_mfma_f32_16x16x32_bf16 %0, %1, %2, %0"
                 : "+v"(d) : "v"(a), "v"(b));
}

__device__ __forceinline__ unsigned short f2bf(float f) {   // RNE f32->bf16
    unsigned u = __float_as_uint(f);
    return (unsigned short)((u + 0x7FFFu + ((u >> 16) & 1u)) >> 16);
}
__device__ __forceinline__ float bf2f(unsigned short h) {
    return __uint_as_float((unsigned)h << 16);
}

// ---------------- weight prep: W1 -> bf16 hi/lo (zero-padded K), W2/W3/W4 -> transposed ----------------
__global__ void prep_weights(const float* __restrict__ W1, const float* __restrict__ W2,
                             const float* __restrict__ W3, const float* __restrict__ W4,
                             unsigned short* __restrict__ W1bh, unsigned short* __restrict__ W1bl,
                             float* __restrict__ W2T, float* __restrict__ W3T,
                             float* __restrict__ W4T) {
    int idx = blockIdx.x * blockDim.x + threadIdx.x;
    int stride = gridDim.x * blockDim.x;
    for (int t = idx; t < H * KP; t += stride) {    // W1bh/W1bl[col][k]
        int c = t >> 8, k = t & 255;
        float v = (k < DIN) ? W1[c * DIN + k] : 0.f;
        unsigned short hi = f2bf(v);
        W1bh[t] = hi;
        W1bl[t] = f2bf(v - bf2f(hi));
    }
    for (int t = idx; t < H * H; t += stride) {     // W2T/W3T[k][c]
        int k = t / H, c = t % H;
        W2T[t] = W2[c * H + k];
        W3T[t] = W3[c * H + k];
    }
    for (int t = idx; t < H * 3; t += stride) {     // W4T[k][o]
        int k = t / 3, o = t % 3;
        W4T[t] = W4[o * H + k];
    }
}

// ---------------- layer 1: split-bf16 MFMA GEMM, fused bias+leaky+stats+count ----------------
// 256 thr = 4 waves; tile 128 rows x 64 cols; wave w owns rows [w*32, w*32+32).
__global__ __launch_bounds__(256)
void gemm1_mfma(const float* __restrict__ x,
                const unsigned short* __restrict__ W1bh, const unsigned short* __restrict__ W1bl,
                const float* __restrict__ b1, const int* __restrict__ grp,
                float* __restrict__ Y, float* __restrict__ sum_, float* __restrict__ sq_,
                int* __restrict__ cnt, int ntiles) {
    __shared__ unsigned short Ah[128 * ASTR];   // 10 KB
    __shared__ unsigned short Al[128 * ASTR];   // 10 KB
    __shared__ unsigned short Bh[64 * ASTR];    // 5 KB
    __shared__ unsigned short Bl[64 * ASTR];    // 5 KB
    __shared__ float sS[GRP_N * H];             // 8 KB
    __shared__ float sQ[GRP_N * H];             // 8 KB
    __shared__ int gl[128];
    __shared__ int cS[GRP_N];
    const int tid = threadIdx.x;
    const int lane = tid & 63, w = tid >> 6;
    const int l15 = lane & 15, lq = lane >> 4;
    for (int t = tid; t < GRP_N * H; t += 256) { sS[t] = 0.f; sQ[t] = 0.f; }
    if (tid < GRP_N) cS[tid] = 0;

    // staging roles: A: 2 threads/row, 16 k each; B: 4 threads/col, 8 k each
    const int arow = tid >> 1;
    const int akb  = (tid & 1) * 16;
    const int bcol = tid >> 2;
    const int bkb  = (tid & 3) * 8;

    float bias4[4];
#pragma unroll
    for (int cf = 0; cf < 4; ++cf) bias4[cf] = b1[cf * 16 + l15];

    for (int tile = blockIdx.x; tile < ntiles; tile += gridDim.x) {
        const int row0 = tile << 7;
        int g = 0;
        if (tid < 128) g = grp[row0 + tid];
        const float* xrow = x + (size_t)(row0 + arow) * DIN;

        // prefetch chunk 0 (global -> regs)
        float xv[16];
#pragma unroll
        for (int q = 0; q < 4; ++q) {
            const int kg = akb + q * 4;
            float4 t4 = (kg < DIN) ? *(const float4*)(xrow + kg) : make_float4(0.f, 0.f, 0.f, 0.f);
            xv[q * 4 + 0] = t4.x; xv[q * 4 + 1] = t4.y;
            xv[q * 4 + 2] = t4.z; xv[q * 4 + 3] = t4.w;
        }
        float4 wh = *(const float4*)(W1bh + bcol * KP + bkb);   // 8 bf16 hi
        float4 wl = *(const float4*)(W1bl + bcol * KP + bkb);   // 8 bf16 lo

        __syncthreads();   // previous tile fully consumed LDS (incl. gl)
        if (tid < 128) { gl[tid] = g; atomicAdd(&cS[g], 1); }

        f32x4 acc[2][4];
#pragma unroll
        for (int rf = 0; rf < 2; ++rf)
#pragma unroll
            for (int cf = 0; cf < 4; ++cf) acc[rf][cf] = (f32x4){0.f, 0.f, 0.f, 0.f};

#pragma unroll 1
        for (int ch = 0; ch < 8; ++ch) {
            if (ch) __syncthreads();       // all waves done reading previous chunk
            // stage A (convert to hi/lo) and B (already bf16)
#pragma unroll
            for (int q = 0; q < 4; ++q) {
                unsigned short h[4], l[4];
#pragma unroll
                for (int j = 0; j < 4; ++j) {
                    float v = xv[q * 4 + j];
                    h[j] = f2bf(v);
                    l[j] = f2bf(v - bf2f(h[j]));
                }
                const int aoff = arow * ASTR + akb + q * 4;
                *(ushort4*)&Ah[aoff] = make_ushort4(h[0], h[1], h[2], h[3]);
                *(ushort4*)&Al[aoff] = make_ushort4(l[0], l[1], l[2], l[3]);
            }
            const int boff = bcol * ASTR + bkb;
            *(float4*)&Bh[boff] = wh;
            *(float4*)&Bl[boff] = wl;
            __syncthreads();               // staged chunk visible
            if (ch < 7) {                  // prefetch next chunk while MFMA runs
                const int kc = (ch + 1) * 32;
#pragma unroll
                for (int q = 0; q < 4; ++q) {
                    const int kg = kc + akb + q * 4;
                    float4 t4 = (kg < DIN) ? *(const float4*)(xrow + kg)
                                           : make_float4(0.f, 0.f, 0.f, 0.f);
                    xv[q * 4 + 0] = t4.x; xv[q * 4 + 1] = t4.y;
                    xv[q * 4 + 2] = t4.z; xv[q * 4 + 3] = t4.w;
                }
                wh = *(const float4*)(W1bh + bcol * KP + kc + bkb);
                wl = *(const float4*)(W1bl + bcol * KP + kc + bkb);
            }
            // load all fragments, then term-major MFMA (dep distance 8)
            short8 afh[2], afl[2], bfh[4], bfl[4];
#pragma unroll
            for (int rf = 0; rf < 2; ++rf) {
                const int ar = w * 32 + rf * 16 + l15;
                afh[rf] = *(const short8*)&Ah[ar * ASTR + lq * 8];
                afl[rf] = *(const short8*)&Al[ar * ASTR + lq * 8];
            }
#pragma unroll
            for (int cf = 0; cf < 4; ++cf) {
                const int bc = cf * 16 + l15;
                bfh[cf] = *(const short8*)&Bh[bc * ASTR + lq * 8];
                bfl[cf] = *(const short8*)&Bl[bc * ASTR + lq * 8];
            }
#pragma unroll
            for (int cf = 0; cf < 4; ++cf)
#pragma unroll
                for (int rf = 0; rf < 2; ++rf) mfma_bf16(acc[rf][cf], afh[rf], bfh[cf]);
#pragma unroll
            for (int cf = 0; cf < 4; ++cf)
#pragma unroll
                for (int rf = 0; rf < 2; ++rf) mfma_bf16(acc[rf][cf], afh[rf], bfl[cf]);
#pragma unroll
            for (int cf = 0; cf < 4; ++cf)
#pragma unroll
                for (int rf = 0; rf < 2; ++rf) mfma_bf16(acc[rf][cf], afl[rf], bfh[cf]);
        }
        // epilogue: bias + leaky, Y store, LDS group stats
        const int rbase = w * 32 + lq * 4;
#pragma unroll
        for (int cf = 0; cf < 4; ++cf) {
            const int col = cf * 16 + l15;
            const float bias = bias4[cf];
#pragma unroll
            for (int rf = 0; rf < 2; ++rf) {
#pragma unroll
                for (int i = 0; i < 4; ++i) {
                    const int rl = rbase + rf * 16 + i;
                    float t = acc[rf][cf][i] + bias;
                    const float o = t >= 0.f ? t : 0.01f * t;
                    Y[(size_t)(row0 + rl) * H + col] = o;
                    const int gr = gl[rl];
                    atomicAdd(&sS[gr * H + col], o);
                    atomicAdd(&sQ[gr * H + col], o * o);
                }
            }
        }
    }
    __syncthreads();
    for (int t = tid; t < GRP_N * H; t += 256) {
        atomicAdd(&sum_[t], sS[t]);
        atomicAdd(&sq_[t], sQ[t]);
    }
    if (tid < GRP_N) atomicAdd(&cnt[tid], cS[tid]);
}

// ---------------- stats -> mu, 1/(std+eps) ----------------
__global__ void finalize_kernel(const float* __restrict__ sum_, const float* __restrict__ sq_,
                                const int* __restrict__ cnt, float* __restrict__ mu_,
                                float* __restrict__ inv_) {
    int t = blockIdx.x * blockDim.x + threadIdx.x;
    if (t >= GRP_N * H) return;
    int g = t >> 6;
    float c = (float)cnt[g];
    float s = sum_[t], q = sq_[t];
    float m = s / fmaxf(c, 1.f);
    float var = fmaxf(q - s * m, 0.f) / fmaxf(c - 1.f, 1.f);
    mu_[t] = m;
    inv_[t] = 1.f / (sqrtf(var) + EPSV);
}

// ---------------- layers 2/3: norm(Y) @ WT -> leaky -> Y (in place), fused stats ----------------
__global__ __launch_bounds__(256)
void gemm_h_fused(float* __restrict__ Y, const int* __restrict__ grp,
                  const float* __restrict__ WT, const float* __restrict__ bias,
                  const float* __restrict__ mu, const float* __restrict__ inv,
                  float* __restrict__ sum_, float* __restrict__ sq_, int ntiles) {
    __shared__ float ZT[16][256];    // 16 KB, BK=16
    __shared__ float WL[H * H];      // 16 KB
    __shared__ float sS[GRP_N * H];  // 8 KB
    __shared__ float sQ[GRP_N * H];  // 8 KB
    __shared__ int gl[256];
    const int tid = threadIdx.x;
    const int rg = tid >> 3, cg = tid & 7;
#pragma unroll
    for (int t = 0; t < 4; ++t)      // preload full 64x64 weight (persists all tiles)
        ((float4*)WL)[tid + t * 256] = ((const float4*)WT)[tid + t * 256];
    for (int t = tid; t < GRP_N * H; t += 256) { sS[t] = 0.f; sQ[t] = 0.f; }

    for (int tile = blockIdx.x; tile < ntiles; tile += gridDim.x) {
        const int row0 = tile << 8;
        const int g = grp[row0 + tid];
        const float* yrow = Y + (size_t)(row0 + tid) * H;
        const float* mrow = mu + g * H;
        const float* irow = inv + g * H;
        float4 v[4], m[4], iv[4];
#pragma unroll
        for (int q = 0; q < 4; ++q) {       // prefetch chunk 0 (16 k's)
            v[q]  = *(const float4*)(yrow + q * 4);
            m[q]  = *(const float4*)(mrow + q * 4);
            iv[q] = *(const float4*)(irow + q * 4);
        }
        __syncthreads();             // prev tile done (covers WL/sS init on tile 0)
        gl[tid] = g;

        float acc[8][8];
#pragma unroll
        for (int r = 0; r < 8; ++r)
#pragma unroll
            for (int c = 0; c < 8; ++c) acc[r][c] = 0.f;

#pragma unroll 1
        for (int ch = 0; ch < 4; ++ch) {    // 4 chunks of BK=16
            if (ch) __syncthreads();
#pragma unroll
            for (int q = 0; q < 4; ++q) {   // normalize at write time
                ZT[q * 4 + 0][tid] = (v[q].x - m[q].x) * iv[q].x;
                ZT[q * 4 + 1][tid] = (v[q].y - m[q].y) * iv[q].y;
                ZT[q * 4 + 2][tid] = (v[q].z - m[q].z) * iv[q].z;
                ZT[q * 4 + 3][tid] = (v[q].w - m[q].w) * iv[q].w;
            }
            __syncthreads();
            if (ch < 3) {
#pragma unroll
                for (int q = 0; q < 4; ++q) {
                    v[q]  = *(const float4*)(yrow + (ch + 1) * 16 + q * 4);
                    m[q]  = *(const float4*)(mrow + (ch + 1) * 16 + q * 4);
                    iv[q] = *(const float4*)(irow + (ch + 1) * 16 + q * 4);
                }
            }
#pragma unroll
            for (int kk = 0; kk < 16; ++kk) {
                const float4 wa = *(const float4*)&WL[(ch * 16 + kk) * 64 + cg * 4];
                const float4 wb = *(const float4*)&WL[(ch * 16 + kk) * 64 + cg * 4 + 32];
                const float4 xa = *(const float4*)&ZT[kk][rg * 4];
                const float4 xb = *(const float4*)&ZT[kk][rg * 4 + 128];
                const float xs[8] = {xa.x, xa.y, xa.z, xa.w, xb.x, xb.y, xb.z, xb.w};
                const float ws8[8] = {wa.x, wa.y, wa.z, wa.w, wb.x, wb.y, wb.z, wb.w};
#pragma unroll
                for (int r = 0; r < 8; ++r)
#pragma unroll
                    for (int c = 0; c < 8; ++c) acc[r][c] += xs[r] * ws8[c];
            }
        }
        // epilogue: bias + leaky, write Y in place, group stats
        const float4 ba = *(const float4*)(bias + cg * 4);
        const float4 bb = *(const float4*)(bias + cg * 4 + 32);
        const float bias8[8] = {ba.x, ba.y, ba.z, ba.w, bb.x, bb.y, bb.z, bb.w};
#pragma unroll
        for (int r = 0; r < 8; ++r) {
            const int lr = rg * 4 + (r & 3) + ((r & 4) ? 128 : 0);
            const int gr = gl[lr];
            float o[8];
#pragma unroll
            for (int c = 0; c < 8; ++c) {
                float t = acc[r][c] + bias8[c];
                o[c] = t >= 0.f ? t : 0.01f * t;
            }
            float* yp = Y + (size_t)(row0 + lr) * H + cg * 4;
            *(float4*)yp        = make_float4(o[0], o[1], o[2], o[3]);
            *(float4*)(yp + 32) = make_float4(o[4], o[5], o[6], o[7]);
            float* Sg = sS + gr * H;
            float* Qg = sQ + gr * H;
#pragma unroll
            for (int c = 0; c < 8; ++c) {
                const int col = cg * 4 + (c & 3) + ((c & 4) ? 32 : 0);
                atomicAdd(&Sg[col], o[c]);
                atomicAdd(&Qg[col], o[c] * o[c]);
            }
        }
    }
    __syncthreads();
    for (int t = tid; t < GRP_N * H; t += 256) {
        atomicAdd(&sum_[t], sS[t]);
        atomicAdd(&sq_[t], sQ[t]);
    }
}

// ---------------- layer 4: norm(Y) @ W4T + b4 -> out[N,3] ----------------
__global__ __launch_bounds__(256)
void gemm4_kernel(const float* __restrict__ Y, const int* __restrict__ grp,
                  const float* __restrict__ W4T, const float* __restrict__ b4,
                  const float* __restrict__ mu, const float* __restrict__ inv,
                  float* __restrict__ out, int n) {
    __shared__ float WL[H * 3];
    const int tid = threadIdx.x;
    if (tid < H * 3) WL[tid] = W4T[tid];
    __syncthreads();
    const int row = blockIdx.x * 256 + tid;
    if (row >= n) return;
    const int g = grp[row];
    float a0 = b4[0], a1 = b4[1], a2 = b4[2];
    const float* yr = Y + (size_t)row * H;
    const float* mr = mu + g * H;
    const float* ir = inv + g * H;
#pragma unroll
    for (int k4 = 0; k4 < H; k4 += 4) {
        float4 v = *(const float4*)(yr + k4);
        float4 m4 = *(const float4*)(mr + k4);
        float4 i4 = *(const float4*)(ir + k4);
        float z[4] = {(v.x - m4.x) * i4.x, (v.y - m4.y) * i4.y,
                      (v.z - m4.z) * i4.z, (v.w - m4.w) * i4.w};
#pragma unroll
        for (int j = 0; j < 4; ++j) {
            a0 += z[j] * WL[(k4 + j) * 3 + 0];
            a1 += z[j] * WL[(k4 + j) * 3 + 1];
            a2 += z[j] * WL[(k4 + j) * 3 + 2];
        }
    }
    out[(size_t)row * 3 + 0] = a0;
    out[(size_t)row * 3 + 1] = a1;
    out[(size_t)row * 3 + 2] = a2;
}

extern "C" void kernel_launch(void* const* d_in, const int* in_sizes, int n_in,
                              void* d_out, int out_size, void* d_ws, size_t ws_size,
                              hipStream_t stream) {
    const float* x  = (const float*)d_in[0];
    const int* grp  = (const int*)d_in[1];
    const float* W1 = (const float*)d_in[2]; const float* b1 = (const float*)d_in[3];
    const float* W2 = (const float*)d_in[4]; const float* b2 = (const float*)d_in[5];
    const float* W3 = (const float*)d_in[6]; const float* b3 = (const float*)d_in[7];
    const float* W4 = (const float*)d_in[8]; const float* b4 = (const float*)d_in[9];
    const int n = in_sizes[1];       // N = 524288, divisible by 256
    const int ntiles1 = n >> 7;      // 128-row tiles for gemm1
    const int ntilesH = n >> 8;      // 256-row tiles for gemm_h

    float* ws = (float*)d_ws;
    float* Y  = ws;                                        // n*64 floats
    unsigned short* W1bh = (unsigned short*)(ws + (size_t)n * H);  // 64*256 bf16
    unsigned short* W1bl = W1bh + H * KP;                          // 64*256 bf16
    float* W2T = (float*)(W1bl + H * KP);                  // 64*64
    float* W3T = W2T + H * H;                              // 64*64
    float* W4T = W3T + H * H;                              // 64*3
    int*   cnt = (int*)(W4T + H * 3);                      // 32
    float* stats = (float*)(cnt + 32);                     // 3 x {sum,sq,mu,inv} x 2048
    float* sum1 = stats + 0 * 8192, *sq1 = sum1 + 2048, *mu1 = sum1 + 4096, *inv1 = sum1 + 6144;
    float* sum2 = stats + 1 * 8192, *sq2 = sum2 + 2048, *mu2 = sum2 + 4096, *inv2 = sum2 + 6144;
    float* sum3 = stats + 2 * 8192, *sq3 = sum3 + 2048, *mu3 = sum3 + 4096, *inv3 = sum3 + 6144;

    // zero cnt + stats accumulators (ws is poisoned 0xAA before every timed launch)
    hipMemsetAsync(cnt, 0, 32 * sizeof(int) + 3 * 8192 * sizeof(float), stream);

    prep_weights<<<32, 256, 0, stream>>>(W1, W2, W3, W4, W1bh, W1bl, W2T, W3T, W4T);

    gemm1_mfma<<<768, 256, 0, stream>>>(x, W1bh, W1bl, b1, grp, Y, sum1, sq1, cnt, ntiles1);
    finalize_kernel<<<8, 256, 0, stream>>>(sum1, sq1, cnt, mu1, inv1);

    gemm_h_fused<<<768, 256, 0, stream>>>(Y, grp, W2T, b2, mu1, inv1, sum2, sq2, ntilesH);
    finalize_kernel<<<8, 256, 0, stream>>>(sum2, sq2, cnt, mu2, inv2);

    gemm_h_fused<<<768, 256, 0, stream>>>(Y, grp, W3T, b3, mu2, inv2, sum3, sq3, ntilesH);
    finalize_kernel<<<8, 256, 0, stream>>>(sum3, sq3, cnt, mu3, inv3);

    gemm4_kernel<<<n / 256, 256, 0, stream>>>(Y, grp, W4T, b4, mu3, inv3,
                                              (float*)d_out, n);
}

// Round 8
// 1729.894 us; speedup vs baseline: 1.0881x; 1.0881x over previous
//
#include <hip/hip_runtime.h>

// N=524288 rows, D_IN=248 (padded to 256), H=64, G=32 groups, OUT=3.
// Pipeline (7 dispatches):
//   prep_weights(split W1/W2/W3 -> bf16 hi/lo, W4 -> transposed)
//   -> gemm1_mfma (split-bf16 3-MFMA, dbuf LDS, fused leaky+stats+count)
//   -> finalize1 -> gemm_h_mfma(W2,+stats2) -> finalize2
//   -> gemm_h_mfma(W3,+stats3) -> finalize3 -> gemm4.
// R4 measured: gemm1 475us with MfmaUtil 4%, VALU 8%, HBM 12% -> latency-bound on the
// serialized (barrier, vmwait+LDS-stage, barrier) window. gemm1 double-buffers LDS
// chunks (one barrier per chunk; vm-wait sits after the MFMA cluster) with frag-order
// LDS [frag][lane][8] so every ds_read_b128 is lane-contiguous (conflict-free).
// gemm_h reuses the identical geometry with K=64 (2 chunks, unrolled; 3 barriers/tile),
// normalizing (y-mu)*inv during A-staging; its B operand (16 KB) is staged to LDS ONCE
// before the tile loop (constant across tiles).
// MFMA layout (verified PASSING in R4):
//   D/C: col = lane&15, row = (lane>>4)*4 + reg
//   A  : row = lane&15, k = (lane>>4)*8 + j
//   B  : col = lane&15, k = (lane>>4)*8 + j

#define GRP_N 32
#define EPSV 1e-8f
constexpr int DIN = 248;
constexpr int KP  = 256;   // padded K for layer 1
constexpr int H   = 64;

typedef __attribute__((ext_vector_type(8))) short short8;   // 8 bf16 raw bits = 4 VGPRs
typedef __attribute__((ext_vector_type(4))) float f32x4;

__device__ __forceinline__ void mfma_bf16(f32x4& d, short8 a, short8 b) {
    asm volatile("v_mfma_f32_16x16x32_bf16 %0, %1, %2, %0"
                 : "+v"(d) : "v"(a), "v"(b));
}

__device__ __forceinline__ unsigned short f2bf(float f) {   // RNE f32->bf16
    unsigned u = __float_as_uint(f);
    return (unsigned short)((u + 0x7FFFu + ((u >> 16) & 1u)) >> 16);
}
__device__ __forceinline__ float bf2f(unsigned short h) {
    return __uint_as_float((unsigned)h << 16);
}

// split 16 floats to hi/lo bf16 and store as two short8 at p and p+128 (shorts)
__device__ __forceinline__ void split_store16(const float* zz,
                                              unsigned short* hp, unsigned short* lp) {
    short8 sh0, sh1, sl0, sl1;
#pragma unroll
    for (int j = 0; j < 8; ++j) {
        unsigned short h0 = f2bf(zz[j]), h1 = f2bf(zz[8 + j]);
        sh0[j] = (short)h0; sl0[j] = (short)f2bf(zz[j] - bf2f(h0));
        sh1[j] = (short)h1; sl1[j] = (short)f2bf(zz[8 + j] - bf2f(h1));
    }
    *(short8*)(hp) = sh0; *(short8*)(hp + 128) = sh1;
    *(short8*)(lp) = sl0; *(short8*)(lp + 128) = sl1;
}

// ---------------- weight prep ----------------
__global__ void prep_weights(const float* __restrict__ W1, const float* __restrict__ W2,
                             const float* __restrict__ W3, const float* __restrict__ W4,
                             unsigned short* __restrict__ W1bh, unsigned short* __restrict__ W1bl,
                             unsigned short* __restrict__ W2bh, unsigned short* __restrict__ W2bl,
                             unsigned short* __restrict__ W3bh, unsigned short* __restrict__ W3bl,
                             float* __restrict__ W4T) {
    int idx = blockIdx.x * blockDim.x + threadIdx.x;
    int stride = gridDim.x * blockDim.x;
    for (int t = idx; t < H * KP; t += stride) {    // W1bh/W1bl[col][k] (pad K to 256)
        int c = t >> 8, k = t & 255;
        float v = (k < DIN) ? W1[c * DIN + k] : 0.f;
        unsigned short hi = f2bf(v);
        W1bh[t] = hi;
        W1bl[t] = f2bf(v - bf2f(hi));
    }
    for (int t = idx; t < H * H; t += stride) {     // W2/W3 natural [c][k] == B layout
        float v2 = W2[t], v3 = W3[t];
        unsigned short h2 = f2bf(v2), h3 = f2bf(v3);
        W2bh[t] = h2; W2bl[t] = f2bf(v2 - bf2f(h2));
        W3bh[t] = h3; W3bl[t] = f2bf(v3 - bf2f(h3));
    }
    for (int t = idx; t < H * 3; t += stride) {     // W4T[k][o]
        int k = t / 3, o = t % 3;
        W4T[t] = W4[o * H + k];
    }
}

// ---------------- layer 1: split-bf16 MFMA GEMM, dbuf, fused bias+leaky+stats+count ----------------
// 256 thr = 4 waves; tile 128 rows x 64 cols; wave w owns rows [w*32, w*32+32).
__global__ __launch_bounds__(256)
void gemm1_mfma(const float* __restrict__ x,
                const unsigned short* __restrict__ W1bh, const unsigned short* __restrict__ W1bl,
                const float* __restrict__ b1, const int* __restrict__ grp,
                float* __restrict__ Y, float* __restrict__ sum_, float* __restrict__ sq_,
                int* __restrict__ cnt, int ntiles) {
    // frag-order LDS: AF[buf][hi/lo][frag(=w*2+rf)*64 + lane][8]; BF[buf][hi/lo][cf*64+lane][8]
    __shared__ unsigned short AF[2][2][4096];   // 32 KB
    __shared__ unsigned short BF[2][2][2048];   // 16 KB
    __shared__ float sS[GRP_N * H];             // 8 KB
    __shared__ float sQ[GRP_N * H];             // 8 KB
    __shared__ int gl[128];
    __shared__ int cS[GRP_N];
    const int tid = threadIdx.x;
    const int lane = tid & 63, w = tid >> 6;
    const int l15 = lane & 15, lq = lane >> 4;
    for (int t = tid; t < GRP_N * H; t += 256) { sS[t] = 0.f; sQ[t] = 0.f; }
    if (tid < GRP_N) cS[tid] = 0;

    // staging roles: A: 2 threads/row (16 k each = 2 frag-rows); B: 4 threads/col (8 k)
    const int arow = tid >> 1;                  // 0..127
    const int akb  = (tid & 1) << 4;            // 0 or 16
    const int abase = ((arow >> 4) * 64 + (akb >> 3) * 16 + (arow & 15)) * 8;
    const int bcol = tid >> 2;                  // 0..63
    const int bkb  = (tid & 3) << 3;            // 0,8,16,24
    const int bbase = ((bcol >> 4) * 64 + (bkb >> 3) * 16 + (bcol & 15)) * 8;

    float bias4[4];
#pragma unroll
    for (int cf = 0; cf < 4; ++cf) bias4[cf] = b1[cf * 16 + l15];

    for (int tile = blockIdx.x; tile < ntiles; tile += gridDim.x) {
        const int row0 = tile << 7;
        int g = 0;
        if (tid < 128) g = grp[row0 + tid];
        const float* xrow = x + (size_t)(row0 + arow) * DIN + akb;

        // load chunk 0 into regs
        float xv[16];
        float4 wh, wl;
        {
#pragma unroll
            for (int q = 0; q < 4; ++q) {
                const int kg = akb + q * 4;
                float4 t4 = (kg < DIN) ? *(const float4*)(xrow + q * 4)
                                       : make_float4(0.f, 0.f, 0.f, 0.f);
                xv[q * 4 + 0] = t4.x; xv[q * 4 + 1] = t4.y;
                xv[q * 4 + 2] = t4.z; xv[q * 4 + 3] = t4.w;
            }
            wh = *(const float4*)(W1bh + bcol * KP + bkb);
            wl = *(const float4*)(W1bl + bcol * KP + bkb);
        }
        __syncthreads();   // tile start: prev tile epilogue fully done
        if (tid < 128) { gl[tid] = g; atomicAdd(&cS[g], 1); }

        // stage chunk 0 -> buf 0
        split_store16(xv, &AF[0][0][abase], &AF[0][1][abase]);
        *(float4*)&BF[0][0][bbase] = wh;
        *(float4*)&BF[0][1][bbase] = wl;
        // issue chunk 1 loads
        {
            const int kc = 32;
#pragma unroll
            for (int q = 0; q < 4; ++q) {
                const int kg = kc + akb + q * 4;
                float4 t4 = (kg < DIN) ? *(const float4*)(xrow + kc + q * 4)
                                       : make_float4(0.f, 0.f, 0.f, 0.f);
                xv[q * 4 + 0] = t4.x; xv[q * 4 + 1] = t4.y;
                xv[q * 4 + 2] = t4.z; xv[q * 4 + 3] = t4.w;
            }
            wh = *(const float4*)(W1bh + bcol * KP + kc + bkb);
            wl = *(const float4*)(W1bl + bcol * KP + kc + bkb);
        }
        __syncthreads();   // buf0 visible

        f32x4 acc[2][4];
#pragma unroll
        for (int rf = 0; rf < 2; ++rf)
#pragma unroll
            for (int cf = 0; cf < 4; ++cf) acc[rf][cf] = (f32x4){0.f, 0.f, 0.f, 0.f};

#pragma unroll 1
        for (int ch = 0; ch < 8; ++ch) {
            const int cur = ch & 1;
            // frags from buf[cur], then MFMA cluster (term-major, dep distance 8)
            short8 afh[2], afl[2], bfh[4], bfl[4];
#pragma unroll
            for (int rf = 0; rf < 2; ++rf) {
                const int fo = ((w * 2 + rf) * 64 + lane) * 8;
                afh[rf] = *(const short8*)&AF[cur][0][fo];
                afl[rf] = *(const short8*)&AF[cur][1][fo];
            }
#pragma unroll
            for (int cf = 0; cf < 4; ++cf) {
                const int fo = (cf * 64 + lane) * 8;
                bfh[cf] = *(const short8*)&BF[cur][0][fo];
                bfl[cf] = *(const short8*)&BF[cur][1][fo];
            }
#pragma unroll
            for (int cf = 0; cf < 4; ++cf)
#pragma unroll
                for (int rf = 0; rf < 2; ++rf) mfma_bf16(acc[rf][cf], afh[rf], bfh[cf]);
#pragma unroll
            for (int cf = 0; cf < 4; ++cf)
#pragma unroll
                for (int rf = 0; rf < 2; ++rf) mfma_bf16(acc[rf][cf], afh[rf], bfl[cf]);
#pragma unroll
            for (int cf = 0; cf < 4; ++cf)
#pragma unroll
                for (int rf = 0; rf < 2; ++rf) mfma_bf16(acc[rf][cf], afl[rf], bfh[cf]);

            if (ch < 7) {
                // stage chunk ch+1 -> buf[cur^1] (vm-wait lands here, after MFMA issue)
                const int nb = cur ^ 1;
                split_store16(xv, &AF[nb][0][abase], &AF[nb][1][abase]);
                *(float4*)&BF[nb][0][bbase] = wh;
                *(float4*)&BF[nb][1][bbase] = wl;
                if (ch < 6) {  // issue chunk ch+2 loads
                    const int kc = (ch + 2) * 32;
#pragma unroll
                    for (int q = 0; q < 4; ++q) {
                        const int kg = kc + akb + q * 4;
                        float4 t4 = (kg < DIN) ? *(const float4*)(xrow + kc + q * 4)
                                               : make_float4(0.f, 0.f, 0.f, 0.f);
                        xv[q * 4 + 0] = t4.x; xv[q * 4 + 1] = t4.y;
                        xv[q * 4 + 2] = t4.z; xv[q * 4 + 3] = t4.w;
                    }
                    wh = *(const float4*)(W1bh + bcol * KP + kc + bkb);
                    wl = *(const float4*)(W1bl + bcol * KP + kc + bkb);
                }
                __syncthreads();
            }
        }
        // epilogue: bias + leaky, Y store, LDS group stats
        const int rbase = w * 32 + lq * 4;
#pragma unroll
        for (int cf = 0; cf < 4; ++cf) {
            const int col = cf * 16 + l15;
            const float bias = bias4[cf];
#pragma unroll
            for (int rf = 0; rf < 2; ++rf) {
#pragma unroll
                for (int i = 0; i < 4; ++i) {
                    const int rl = rbase + rf * 16 + i;
                    float t = acc[rf][cf][i] + bias;
                    const float o = t >= 0.f ? t : 0.01f * t;
                    Y[(size_t)(row0 + rl) * H + col] = o;
                    const int gr = gl[rl];
                    atomicAdd(&sS[gr * H + col], o);
                    atomicAdd(&sQ[gr * H + col], o * o);
                }
            }
        }
    }
    __syncthreads();
    for (int t = tid; t < GRP_N * H; t += 256) {
        atomicAdd(&sum_[t], sS[t]);
        atomicAdd(&sq_[t], sQ[t]);
    }
    if (tid < GRP_N) atomicAdd(&cnt[tid], cS[tid]);
}

// ---------------- stats -> mu, 1/(std+eps) (fp64 internals) ----------------
__global__ void finalize_kernel(const float* __restrict__ sum_, const float* __restrict__ sq_,
                                const int* __restrict__ cnt, float* __restrict__ mu_,
                                float* __restrict__ inv_) {
    int t = blockIdx.x * blockDim.x + threadIdx.x;
    if (t >= GRP_N * H) return;
    int g = t >> 6;
    double c = (double)cnt[g];
    double s = (double)sum_[t], q = (double)sq_[t];
    double m = s / fmax(c, 1.0);
    double var = fmax(q - s * m, 0.0) / fmax(c - 1.0, 1.0);
    mu_[t] = (float)m;
    inv_[t] = (float)(1.0 / (sqrt(var) + (double)EPSV));
}

// ---------------- layers 2/3: norm(Y) @ W^T -> leaky -> Y (in place), MFMA, fused stats ----------------
// Same geometry as gemm1: 4 waves, 128-row x 64-col tile, K=64 (2 chunks, unrolled).
// B (weights) staged to LDS once before the tile loop (constant across tiles).
__global__ __launch_bounds__(256)
void gemm_h_mfma(float* __restrict__ Y, const int* __restrict__ grp,
                 const unsigned short* __restrict__ Wbh, const unsigned short* __restrict__ Wbl,
                 const float* __restrict__ bias, const float* __restrict__ mu,
                 const float* __restrict__ inv,
                 float* __restrict__ sum_, float* __restrict__ sq_, int ntiles) {
    __shared__ unsigned short AF[2][2][4096];   // 32 KB
    __shared__ unsigned short BF[2][2][2048];   // 16 KB (chunk0 in [0], chunk1 in [1])
    __shared__ float sS[GRP_N * H];             // 8 KB
    __shared__ float sQ[GRP_N * H];             // 8 KB
    __shared__ int gl[128];
    const int tid = threadIdx.x;
    const int lane = tid & 63, w = tid >> 6;
    const int l15 = lane & 15, lq = lane >> 4;
    for (int t = tid; t < GRP_N * H; t += 256) { sS[t] = 0.f; sQ[t] = 0.f; }

    const int arow = tid >> 1;
    const int akb  = (tid & 1) << 4;
    const int abase = ((arow >> 4) * 64 + (akb >> 3) * 16 + (arow & 15)) * 8;
    const int bcol = tid >> 2;
    const int bkb  = (tid & 3) << 3;
    const int bbase = ((bcol >> 4) * 64 + (bkb >> 3) * 16 + (bcol & 15)) * 8;

    // stage B once: both K-chunks, hi+lo (first tile-start barrier makes it visible)
    {
        *(float4*)&BF[0][0][bbase] = *(const float4*)(Wbh + bcol * H + bkb);
        *(float4*)&BF[0][1][bbase] = *(const float4*)(Wbl + bcol * H + bkb);
        *(float4*)&BF[1][0][bbase] = *(const float4*)(Wbh + bcol * H + 32 + bkb);
        *(float4*)&BF[1][1][bbase] = *(const float4*)(Wbl + bcol * H + 32 + bkb);
    }

    float bias4[4];
#pragma unroll
    for (int cf = 0; cf < 4; ++cf) bias4[cf] = bias[cf * 16 + l15];

    for (int tile = blockIdx.x; tile < ntiles; tile += gridDim.x) {
        const int row0 = tile << 7;
        int g = 0;
        if (tid < 128) g = grp[row0 + tid];
        const int ag = grp[row0 + arow];        // staging row's group
        const float* yrow = Y + (size_t)(row0 + arow) * H + akb;
        const float* mrow = mu + ag * H + akb;
        const float* irow = inv + ag * H + akb;

        // chunk 0 y-loads (k in [akb, akb+16)); mu/inv loaded at stage time (L1-hot 8KB)
        float4 y0 = *(const float4*)(yrow);
        float4 y1 = *(const float4*)(yrow + 4);
        float4 y2 = *(const float4*)(yrow + 8);
        float4 y3 = *(const float4*)(yrow + 12);

        __syncthreads();   // tile start: prev tile epilogue done; B staging visible (tile 0)
        if (tid < 128) gl[tid] = g;

        // stage chunk 0 -> AF buf 0 (normalize + hi/lo split)
        {
            float4 m0 = *(const float4*)(mrow),     m1 = *(const float4*)(mrow + 4);
            float4 m2 = *(const float4*)(mrow + 8), m3 = *(const float4*)(mrow + 12);
            float4 i0 = *(const float4*)(irow),     i1 = *(const float4*)(irow + 4);
            float4 i2 = *(const float4*)(irow + 8), i3 = *(const float4*)(irow + 12);
            float zz[16];
            zz[0] = (y0.x - m0.x) * i0.x; zz[1] = (y0.y - m0.y) * i0.y;
            zz[2] = (y0.z - m0.z) * i0.z; zz[3] = (y0.w - m0.w) * i0.w;
            zz[4] = (y1.x - m1.x) * i1.x; zz[5] = (y1.y - m1.y) * i1.y;
            zz[6] = (y1.z - m1.z) * i1.z; zz[7] = (y1.w - m1.w) * i1.w;
            zz[8] = (y2.x - m2.x) * i2.x; zz[9] = (y2.y - m2.y) * i2.y;
            zz[10] = (y2.z - m2.z) * i2.z; zz[11] = (y2.w - m2.w) * i2.w;
            zz[12] = (y3.x - m3.x) * i3.x; zz[13] = (y3.y - m3.y) * i3.y;
            zz[14] = (y3.z - m3.z) * i3.z; zz[15] = (y3.w - m3.w) * i3.w;
            split_store16(zz, &AF[0][0][abase], &AF[0][1][abase]);
        }
        // issue chunk 1 loads (k + 32)
        y0 = *(const float4*)(yrow + 32);
        y1 = *(const float4*)(yrow + 36);
        y2 = *(const float4*)(yrow + 40);
        y3 = *(const float4*)(yrow + 44);
        __syncthreads();   // buf0 visible

        f32x4 acc[2][4];
#pragma unroll
        for (int rf = 0; rf < 2; ++rf)
#pragma unroll
            for (int cf = 0; cf < 4; ++cf) acc[rf][cf] = (f32x4){0.f, 0.f, 0.f, 0.f};

        // ---- MFMA chunk 0 ----
        {
            short8 afh[2], afl[2], bfh[4], bfl[4];
#pragma unroll
            for (int rf = 0; rf < 2; ++rf) {
                const int fo = ((w * 2 + rf) * 64 + lane) * 8;
                afh[rf] = *(const short8*)&AF[0][0][fo];
                afl[rf] = *(const short8*)&AF[0][1][fo];
            }
#pragma unroll
            for (int cf = 0; cf < 4; ++cf) {
                const int fo = (cf * 64 + lane) * 8;
                bfh[cf] = *(const short8*)&BF[0][0][fo];
                bfl[cf] = *(const short8*)&BF[0][1][fo];
            }
#pragma unroll
            for (int cf = 0; cf < 4; ++cf)
#pragma unroll
                for (int rf = 0; rf < 2; ++rf) mfma_bf16(acc[rf][cf], afh[rf], bfh[cf]);
#pragma unroll
            for (int cf = 0; cf < 4; ++cf)
#pragma unroll
                for (int rf = 0; rf < 2; ++rf) mfma_bf16(acc[rf][cf], afh[rf], bfl[cf]);
#pragma unroll
            for (int cf = 0; cf < 4; ++cf)
#pragma unroll
                for (int rf = 0; rf < 2; ++rf) mfma_bf16(acc[rf][cf], afl[rf], bfh[cf]);
        }
        // stage chunk 1 -> AF buf 1 (vm-wait for chunk1 y-loads lands here, after MFMA issue)
        {
            float4 m0 = *(const float4*)(mrow + 32), m1 = *(const float4*)(mrow + 36);
            float4 m2 = *(const float4*)(mrow + 40), m3 = *(const float4*)(mrow + 44);
            float4 i0 = *(const float4*)(irow + 32), i1 = *(const float4*)(irow + 36);
            float4 i2 = *(const float4*)(irow + 40), i3 = *(const float4*)(irow + 44);
            float zz[16];
            zz[0] = (y0.x - m0.x) * i0.x; zz[1] = (y0.y - m0.y) * i0.y;
            zz[2] = (y0.z - m0.z) * i0.z; zz[3] = (y0.w - m0.w) * i0.w;
            zz[4] = (y1.x - m1.x) * i1.x; zz[5] = (y1.y - m1.y) * i1.y;
            zz[6] = (y1.z - m1.z) * i1.z; zz[7] = (y1.w - m1.w) * i1.w;
            zz[8] = (y2.x - m2.x) * i2.x; zz[9] = (y2.y - m2.y) * i2.y;
            zz[10] = (y2.z - m2.z) * i2.z; zz[11] = (y2.w - m2.w) * i2.w;
            zz[12] = (y3.x - m3.x) * i3.x; zz[13] = (y3.y - m3.y) * i3.y;
            zz[14] = (y3.z - m3.z) * i3.z; zz[15] = (y3.w - m3.w) * i3.w;
            split_store16(zz, &AF[1][0][abase], &AF[1][1][abase]);
        }
        __syncthreads();   // buf1 visible (also: all tile y-reads consumed before epilogue writes)

        // ---- MFMA chunk 1 ----
        {
            short8 afh[2], afl[2], bfh[4], bfl[4];
#pragma unroll
            for (int rf = 0; rf < 2; ++rf) {
                const int fo = ((w * 2 + rf) * 64 + lane) * 8;
                afh[rf] = *(const short8*)&AF[1][0][fo];
                afl[rf] = *(const short8*)&AF[1][1][fo];
            }
#pragma unroll
            for (int cf = 0; cf < 4; ++cf) {
                const int fo = (cf * 64 + lane) * 8;
                bfh[cf] = *(const short8*)&BF[1][0][fo];
                bfl[cf] = *(const short8*)&BF[1][1][fo];
            }
#pragma unroll
            for (int cf = 0; cf < 4; ++cf)
#pragma unroll
                for (int rf = 0; rf < 2; ++rf) mfma_bf16(acc[rf][cf], afh[rf], bfh[cf]);
#pragma unroll
            for (int cf = 0; cf < 4; ++cf)
#pragma unroll
                for (int rf = 0; rf < 2; ++rf) mfma_bf16(acc[rf][cf], afh[rf], bfl[cf]);
#pragma unroll
            for (int cf = 0; cf < 4; ++cf)
#pragma unroll
                for (int rf = 0; rf < 2; ++rf) mfma_bf16(acc[rf][cf], afl[rf], bfh[cf]);
        }
        // epilogue: bias + leaky, in-place Y store, LDS group stats
        const int rbase = w * 32 + lq * 4;
#pragma unroll
        for (int cf = 0; cf < 4; ++cf) {
            const int col = cf * 16 + l15;
            const float bv = bias4[cf];
#pragma unroll
            for (int rf = 0; rf < 2; ++rf) {
#pragma unroll
                for (int i = 0; i < 4; ++i) {
                    const int rl = rbase + rf * 16 + i;
                    float t = acc[rf][cf][i] + bv;
                    const float o = t >= 0.f ? t : 0.01f * t;
                    Y[(size_t)(row0 + rl) * H + col] = o;
                    const int gr = gl[rl];
                    atomicAdd(&sS[gr * H + col], o);
                    atomicAdd(&sQ[gr * H + col], o * o);
                }
            }
        }
    }
    __syncthreads();
    for (int t = tid; t < GRP_N * H; t += 256) {
        atomicAdd(&sum_[t], sS[t]);
        atomicAdd(&sq_[t], sQ[t]);
    }
}

// ---------------- layer 4: norm(Y) @ W4T + b4 -> out[N,3] ----------------
// 4 lanes per row (16B/lane coalesced), quad shfl_xor reduction.
__global__ __launch_bounds__(256)
void gemm4_kernel(const float* __restrict__ Y, const int* __restrict__ grp,
                  const float* __restrict__ W4T, const float* __restrict__ b4,
                  const float* __restrict__ mu, const float* __restrict__ inv,
                  float* __restrict__ out, int nblk) {
    __shared__ float WL[H * 3];
    const int tid = threadIdx.x;
    if (tid < H * 3) WL[tid] = W4T[tid];
    __syncthreads();
    const int l = tid & 63, wv = tid >> 6;
    const int qr = l >> 2, qc = l & 3, seg = qc * 16;
    const float bcst = (qc < 3) ? b4[qc] : 0.f;
    for (int rb = blockIdx.x; rb < nblk; rb += gridDim.x) {
        const int row = (rb << 6) + (wv << 4) + qr;
        const int g = grp[row];
        const float* yr = Y + (size_t)row * H + seg;
        const float* mr = mu + g * H + seg;
        const float* ir = inv + g * H + seg;
        float a0 = 0.f, a1 = 0.f, a2 = 0.f;
#pragma unroll
        for (int q4 = 0; q4 < 4; ++q4) {
            float4 v = *(const float4*)(yr + q4 * 4);
            float4 m4 = *(const float4*)(mr + q4 * 4);
            float4 i4 = *(const float4*)(ir + q4 * 4);
            float z[4] = {(v.x - m4.x) * i4.x, (v.y - m4.y) * i4.y,
                          (v.z - m4.z) * i4.z, (v.w - m4.w) * i4.w};
#pragma unroll
            for (int j = 0; j < 4; ++j) {
                const float* wl = &WL[(seg + q4 * 4 + j) * 3];
                a0 += z[j] * wl[0];
                a1 += z[j] * wl[1];
                a2 += z[j] * wl[2];
            }
        }
        a0 += __shfl_xor(a0, 1); a0 += __shfl_xor(a0, 2);
        a1 += __shfl_xor(a1, 1); a1 += __shfl_xor(a1, 2);
        a2 += __shfl_xor(a2, 1); a2 += __shfl_xor(a2, 2);
        const float res = (qc == 0) ? a0 : ((qc == 1) ? a1 : a2);
        if (qc < 3) out[(size_t)row * 3 + qc] = res + bcst;
    }
}

extern "C" void kernel_launch(void* const* d_in, const int* in_sizes, int n_in,
                              void* d_out, int out_size, void* d_ws, size_t ws_size,
                              hipStream_t stream) {
    const float* x  = (const float*)d_in[0];
    const int* grp  = (const int*)d_in[1];
    const float* W1 = (const float*)d_in[2]; const float* b1 = (const float*)d_in[3];
    const float* W2 = (const float*)d_in[4]; const float* b2 = (const float*)d_in[5];
    const float* W3 = (const float*)d_in[6]; const float* b3 = (const float*)d_in[7];
    const float* W4 = (const float*)d_in[8]; const float* b4 = (const float*)d_in[9];
    const int n = in_sizes[1];       // N = 524288, divisible by 256
    const int ntiles1 = n >> 7;      // 128-row tiles (gemm1 and gemm_h)
    const int nblk4   = n >> 6;      // 64-row blocks for gemm4

    float* ws = (float*)d_ws;
    float* Y  = ws;                                                // n*64 floats
    unsigned short* W1bh = (unsigned short*)(ws + (size_t)n * H);  // 64*256
    unsigned short* W1bl = W1bh + H * KP;
    unsigned short* W2bh = W1bl + H * KP;                          // 64*64
    unsigned short* W2bl = W2bh + H * H;
    unsigned short* W3bh = W2bl + H * H;
    unsigned short* W3bl = W3bh + H * H;
    float* W4T = (float*)(W3bl + H * H);                           // 64*3
    int*   cnt = (int*)(W4T + H * 3);                              // 32
    float* stats = (float*)(cnt + 32);                             // 3 x {sum,sq,mu,inv} x 2048
    float* sum1 = stats + 0 * 8192, *sq1 = sum1 + 2048, *mu1 = sum1 + 4096, *inv1 = sum1 + 6144;
    float* sum2 = stats + 1 * 8192, *sq2 = sum2 + 2048, *mu2 = sum2 + 4096, *inv2 = sum2 + 6144;
    float* sum3 = stats + 2 * 8192, *sq3 = sum3 + 2048, *mu3 = sum3 + 4096, *inv3 = sum3 + 6144;

    // zero cnt + stats accumulators (ws is poisoned 0xAA before every timed launch)
    hipMemsetAsync(cnt, 0, 32 * sizeof(int) + 3 * 8192 * sizeof(float), stream);

    prep_weights<<<32, 256, 0, stream>>>(W1, W2, W3, W4, W1bh, W1bl,
                                         W2bh, W2bl, W3bh, W3bl, W4T);

    gemm1_mfma<<<512, 256, 0, stream>>>(x, W1bh, W1bl, b1, grp, Y, sum1, sq1, cnt, ntiles1);
    finalize_kernel<<<8, 256, 0, stream>>>(sum1, sq1, cnt, mu1, inv1);

    gemm_h_mfma<<<512, 256, 0, stream>>>(Y, grp, W2bh, W2bl, b2, mu1, inv1, sum2, sq2, ntiles1);
    finalize_kernel<<<8, 256, 0, stream>>>(sum2, sq2, cnt, mu2, inv2);

    gemm_h_mfma<<<512, 256, 0, stream>>>(Y, grp, W3bh, W3bl, b3, mu2, inv2, sum3, sq3, ntiles1);
    finalize_kernel<<<8, 256, 0, stream>>>(sum3, sq3, cnt, mu3, inv3);

    gemm4_kernel<<<2048, 256, 0, stream>>>(Y, grp, W4T, b4, mu3, inv3,
                                           (float*)d_out, nblk4);
}